// Round 1
// baseline (409.387 us; speedup 1.0000x reference)
//
#include <hip/hip_runtime.h>
#include <hip/hip_bf16.h>

typedef __attribute__((ext_vector_type(8))) short short8;     // 8 bf16 (MFMA frag)
typedef __attribute__((ext_vector_type(4))) float f32x4;      // MFMA acc frag
typedef __attribute__((ext_vector_type(8))) unsigned short u16x8;
typedef __attribute__((ext_vector_type(4))) unsigned short u16x4;

#define MFMA16(A, B, C) __builtin_amdgcn_mfma_f32_16x16x32_bf16(A, B, C, 0, 0, 0)

static __device__ __forceinline__ unsigned short f2bf(float f) {
    unsigned int u = __builtin_bit_cast(unsigned int, f);
    u += 0x7FFF + ((u >> 16) & 1);   // RNE
    return (unsigned short)(u >> 16);
}

// ---------------------------------------------------------------------------
// Weight transpose + cast: W [K][N] fp32  ->  Wt [N][K] bf16
// ---------------------------------------------------------------------------
__global__ void wtrans(const float* __restrict__ W, unsigned short* __restrict__ Wt,
                       int K, int N) {
    __shared__ float tl[32][33];
    const int n0 = blockIdx.x * 32, k0 = blockIdx.y * 32;
    const int tx = threadIdx.x, ty = threadIdx.y;
#pragma unroll
    for (int i = 0; i < 4; i++)
        tl[ty + 8 * i][tx] = W[(long)(k0 + ty + 8 * i) * N + n0 + tx];
    __syncthreads();
#pragma unroll
    for (int i = 0; i < 4; i++)
        Wt[(long)(n0 + ty + 8 * i) * K + k0 + tx] = f2bf(tl[tx][ty + 8 * i]);
}

// ---------------------------------------------------------------------------
// LayerNorm: fp32 [rows][768] -> bf16 [rows][768].  One wave per row.
// ---------------------------------------------------------------------------
__global__ __launch_bounds__(256)
void ln_fwd(const float* __restrict__ x, const float* __restrict__ gw,
            const float* __restrict__ bw, unsigned short* __restrict__ out) {
    const int row = blockIdx.x * 4 + (threadIdx.x >> 6);
    const int ln = threadIdx.x & 63;
    const float4* xr = (const float4*)(x + (long)row * 768);
    float4 v[3];
    float s = 0.f;
#pragma unroll
    for (int j = 0; j < 3; j++) {
        v[j] = xr[ln + 64 * j];
        s += v[j].x + v[j].y + v[j].z + v[j].w;
    }
#pragma unroll
    for (int off = 32; off >= 1; off >>= 1) s += __shfl_xor(s, off);
    const float mean = s * (1.0f / 768.0f);
    float sq = 0.f;
#pragma unroll
    for (int j = 0; j < 3; j++) {
        float a = v[j].x - mean, b = v[j].y - mean, c = v[j].z - mean, d = v[j].w - mean;
        sq += a * a + b * b + c * c + d * d;
    }
#pragma unroll
    for (int off = 32; off >= 1; off >>= 1) sq += __shfl_xor(sq, off);
    const float rstd = rsqrtf(sq * (1.0f / 768.0f) + 1e-5f);
#pragma unroll
    for (int j = 0; j < 3; j++) {
        const int c = ln + 64 * j;
        float4 gg = ((const float4*)gw)[c];
        float4 bb = ((const float4*)bw)[c];
        u16x4 o;
        o[0] = f2bf((v[j].x - mean) * rstd * gg.x + bb.x);
        o[1] = f2bf((v[j].y - mean) * rstd * gg.y + bb.y);
        o[2] = f2bf((v[j].z - mean) * rstd * gg.z + bb.z);
        o[3] = f2bf((v[j].w - mean) * rstd * gg.w + bb.w);
        *(u16x4*)(out + (long)row * 768 + c * 4) = o;
    }
}

// ---------------------------------------------------------------------------
// GEMM  C[M,N] = A[M,K] (bf16) x Bt[N,K]^T (bf16) + bias, fused epilogues.
// 128x128 tile, BK=32, 4 waves, each wave 64x64 via 4x4 16x16x32 MFMAs.
// MODE 1: qkv  -> bf16 out, cols<768 scaled by 0.125 (q/sqrt(D))
// MODE 2: proj -> fp32 out = acc + bias + resid
// MODE 3: fc   -> bf16 out = gelu(acc + bias)
// MODE 4: fc2  -> fp32 out = acc + bias + resid
// ---------------------------------------------------------------------------
template <int MODE>
__global__ __launch_bounds__(256)
void gemm_bt(const unsigned short* __restrict__ A, const unsigned short* __restrict__ Bt,
             const float* __restrict__ bias, const float* __restrict__ resid,
             void* __restrict__ Out, int M, int N, int K) {
    __shared__ unsigned short Al[128 * 40];   // +8 pad: 80B rows, 16B aligned
    __shared__ unsigned short Bl[128 * 40];
    const int tid = threadIdx.x;
    const int wv = tid >> 6, ln = tid & 63;
    const int wr = wv >> 1, wc = wv & 1;
    const int g = ln >> 4, r = ln & 15;
    const long mbase = (long)blockIdx.x * 128;
    const long nbase = (long)blockIdx.y * 128;

    f32x4 acc[4][4];
    const f32x4 zero = {0.f, 0.f, 0.f, 0.f};
#pragma unroll
    for (int m = 0; m < 4; m++)
#pragma unroll
        for (int n = 0; n < 4; n++) acc[m][n] = zero;

    for (int k0 = 0; k0 < K; k0 += 32) {
        __syncthreads();
#pragma unroll
        for (int p = 0; p < 2; p++) {
            int idx = p * 256 + tid;
            int row = idx >> 2, cc = (idx & 3) * 8;
            *(u16x8*)(Al + row * 40 + cc) = *(const u16x8*)(A + (mbase + row) * K + k0 + cc);
            *(u16x8*)(Bl + row * 40 + cc) = *(const u16x8*)(Bt + (nbase + row) * K + k0 + cc);
        }
        __syncthreads();
        short8 af[4], bfr[4];
#pragma unroll
        for (int m = 0; m < 4; m++)
            af[m] = *(const short8*)(Al + (wr * 64 + m * 16 + r) * 40 + g * 8);
#pragma unroll
        for (int n = 0; n < 4; n++)
            bfr[n] = *(const short8*)(Bl + (wc * 64 + n * 16 + r) * 40 + g * 8);
#pragma unroll
        for (int m = 0; m < 4; m++)
#pragma unroll
            for (int n = 0; n < 4; n++) acc[m][n] = MFMA16(af[m], bfr[n], acc[m][n]);
    }

#pragma unroll
    for (int n = 0; n < 4; n++) {
        const long col = nbase + wc * 64 + n * 16 + r;
        const float bc = bias[col];
#pragma unroll
        for (int m = 0; m < 4; m++) {
#pragma unroll
            for (int i = 0; i < 4; i++) {
                const long row = mbase + wr * 64 + m * 16 + g * 4 + i;
                float v = acc[m][n][i] + bc;
                if constexpr (MODE == 1) {
                    if (col < 768) v *= 0.125f;
                    ((unsigned short*)Out)[row * N + col] = f2bf(v);
                } else if constexpr (MODE == 2 || MODE == 4) {
                    ((float*)Out)[row * N + col] = v + resid[row * N + col];
                } else {
                    float u = 0.7978845608028654f * (v + 0.044715f * v * v * v);
                    float gl = 0.5f * v * (1.0f + tanhf(u));
                    ((unsigned short*)Out)[row * N + col] = f2bf(gl);
                }
            }
        }
    }
}

// ---------------------------------------------------------------------------
// V transpose: qkv[b][t][1536 + h*64 + d] -> vT[bh][d][t]   (bf16)
// mod-9 block permutation inside 72-elem LDS rows keeps both sides ~conflict-free.
// ---------------------------------------------------------------------------
__global__ __launch_bounds__(256)
void vtrans(const unsigned short* __restrict__ qkv, unsigned short* __restrict__ vT) {
    const int t0 = blockIdx.x * 64;
    const int bh = blockIdx.y;
    const int b = bh / 12, h = bh % 12;
    __shared__ unsigned short tl[64 * 72];
    const int tid = threadIdx.x;
#pragma unroll
    for (int p = 0; p < 2; p++) {
        int idx = p * 256 + tid;
        int row = idx >> 3, blk = idx & 7;
        int sb = (blk + row) % 9;
        *(u16x8*)(tl + row * 72 + sb * 8) =
            *(const u16x8*)(qkv + ((long)(b * 2048 + t0 + row)) * 2304 + 1536 + h * 64 + blk * 8);
    }
    __syncthreads();
#pragma unroll
    for (int p = 0; p < 2; p++) {
        int idx = p * 256 + tid;
        int d = idx >> 3, tc = (idx & 7) * 8;
        u16x8 v;
#pragma unroll
        for (int j = 0; j < 8; j++) {
            int t = tc + j;
            int sb = ((d >> 3) + t) % 9;
            v[j] = tl[t * 72 + sb * 8 + (d & 7)];
        }
        *(u16x8*)(vT + ((long)(bh * 64 + d)) * 2048 + t0 + tc) = v;
    }
}

// ---------------------------------------------------------------------------
// Flash attention fwd (causal). One block = one (b,h), 64 q rows, 4 waves.
// Swapped QK^T: S^T = mfma(A=K, B=Q) -> per-lane row softmax (2 shuffles).
// q already scaled by 1/8 in the QKV epilogue.
// ---------------------------------------------------------------------------
__global__ __launch_bounds__(256)
void attn_fwd(const unsigned short* __restrict__ qkv, const unsigned short* __restrict__ vT,
              unsigned short* __restrict__ y) {
    const int qt = (int)gridDim.x - 1 - (int)blockIdx.x;   // big tiles dispatched first
    const int bh = blockIdx.y;
    const int b = bh / 12, h = bh % 12;
    const int q0 = qt * 64;
    __shared__ unsigned short Ql[64 * 72], Kl[64 * 72], Vl[64 * 72], Pl[64 * 72];
    const int tid = threadIdx.x;
    const int wv = tid >> 6, ln = tid & 63;
    const int g = ln >> 4, r = ln & 15;
    const f32x4 zero = {0.f, 0.f, 0.f, 0.f};

#pragma unroll
    for (int p = 0; p < 2; p++) {
        int idx = p * 256 + tid;
        int row = idx >> 3, cc = (idx & 7) * 8;
        *(u16x8*)(Ql + row * 72 + cc) =
            *(const u16x8*)(qkv + ((long)(b * 2048 + q0 + row)) * 2304 + h * 64 + cc);
    }
    __syncthreads();
    short8 bq0 = *(const short8*)(Ql + (wv * 16 + r) * 72 + g * 8);
    short8 bq1 = *(const short8*)(Ql + (wv * 16 + r) * 72 + 32 + g * 8);

    float mrow = -1e30f, lrow = 0.0f;
    f32x4 oacc[4];
#pragma unroll
    for (int f = 0; f < 4; f++) oacc[f] = zero;

    for (int kt = 0; kt <= qt; ++kt) {
        __syncthreads();
#pragma unroll
        for (int p = 0; p < 2; p++) {
            int idx = p * 256 + tid;
            int row = idx >> 3, cc = (idx & 7) * 8;
            *(u16x8*)(Kl + row * 72 + cc) =
                *(const u16x8*)(qkv + ((long)(b * 2048 + kt * 64 + row)) * 2304 + 768 + h * 64 + cc);
            *(u16x8*)(Vl + row * 72 + cc) =
                *(const u16x8*)(vT + ((long)(bh * 64 + row)) * 2048 + kt * 64 + cc);
        }
        __syncthreads();

        f32x4 s[4];
#pragma unroll
        for (int kf = 0; kf < 4; kf++) {
            short8 a0 = *(const short8*)(Kl + (kf * 16 + r) * 72 + g * 8);
            short8 a1 = *(const short8*)(Kl + (kf * 16 + r) * 72 + 32 + g * 8);
            s[kf] = MFMA16(a0, bq0, zero);
            s[kf] = MFMA16(a1, bq1, s[kf]);
        }
        if (kt == qt) {   // diagonal tile: mask k_local > q_local
            const int ql = wv * 16 + r;
#pragma unroll
            for (int kf = 0; kf < 4; kf++)
#pragma unroll
                for (int i = 0; i < 4; i++)
                    if (kf * 16 + g * 4 + i > ql) s[kf][i] = -1e30f;
        }
        // ---- online softmax (row = q, held per lane across 16 regs + 4 groups)
        float tmax = s[0][0];
#pragma unroll
        for (int kf = 0; kf < 4; kf++)
#pragma unroll
            for (int i = 0; i < 4; i++) tmax = fmaxf(tmax, s[kf][i]);
        tmax = fmaxf(tmax, __shfl_xor(tmax, 16));
        tmax = fmaxf(tmax, __shfl_xor(tmax, 32));
        const float mnew = fmaxf(mrow, tmax);
        const float rs = __expf(mrow - mnew);
        float pv[4][4];
        float psum = 0.f;
#pragma unroll
        for (int kf = 0; kf < 4; kf++)
#pragma unroll
            for (int i = 0; i < 4; i++) {
                pv[kf][i] = __expf(s[kf][i] - mnew);
                psum += pv[kf][i];
            }
        psum += __shfl_xor(psum, 16);
        psum += __shfl_xor(psum, 32);
        lrow = lrow * rs + psum;
        mrow = mnew;
#pragma unroll
        for (int f = 0; f < 4; f++) oacc[f] = oacc[f] * rs;

        // ---- P^T -> LDS (wave-local rows), packed b64 writes
        const int q = wv * 16 + r;
#pragma unroll
        for (int kf = 0; kf < 4; kf++) {
            u16x4 pk;
#pragma unroll
            for (int i = 0; i < 4; i++) pk[i] = f2bf(pv[kf][i]);
            *(u16x4*)(Pl + q * 72 + kf * 16 + g * 4) = pk;
        }
        short8 pb0 = *(const short8*)(Pl + q * 72 + g * 8);
        short8 pb1 = *(const short8*)(Pl + q * 72 + 32 + g * 8);
#pragma unroll
        for (int f = 0; f < 4; f++) {
            short8 va0 = *(const short8*)(Vl + (f * 16 + r) * 72 + g * 8);
            short8 va1 = *(const short8*)(Vl + (f * 16 + r) * 72 + 32 + g * 8);
            oacc[f] = MFMA16(va0, pb0, oacc[f]);
            oacc[f] = MFMA16(va1, pb1, oacc[f]);
        }
    }

    // ---- epilogue: O^T frags -> LDS (reuse Pl) -> coalesced global
    const float inv = 1.0f / lrow;
    const int q = wv * 16 + r;
#pragma unroll
    for (int f = 0; f < 4; f++) {
        u16x4 o4;
#pragma unroll
        for (int i = 0; i < 4; i++) o4[i] = f2bf(oacc[f][i] * inv);
        *(u16x4*)(Pl + q * 72 + f * 16 + g * 4) = o4;
    }
    __syncthreads();
#pragma unroll
    for (int p = 0; p < 2; p++) {
        int idx = p * 256 + tid;
        int row = idx >> 3, cc = (idx & 7) * 8;
        *(u16x8*)(y + ((long)(b * 2048 + q0 + row)) * 768 + h * 64 + cc) =
            *(const u16x8*)(Pl + row * 72 + cc);
    }
}

// ---------------------------------------------------------------------------
extern "C" void kernel_launch(void* const* d_in, const int* in_sizes, int n_in,
                              void* d_out, int out_size, void* d_ws, size_t ws_size,
                              hipStream_t stream) {
    const float* x      = (const float*)d_in[0];
    const float* ln1_g  = (const float*)d_in[1];
    const float* ln1_b  = (const float*)d_in[2];
    const float* W_attn = (const float*)d_in[3];
    const float* b_attn = (const float*)d_in[4];
    const float* W_proj = (const float*)d_in[5];
    const float* b_proj = (const float*)d_in[6];
    const float* ln2_g  = (const float*)d_in[7];
    const float* ln2_b  = (const float*)d_in[8];
    const float* W_fc   = (const float*)d_in[9];
    const float* b_fc   = (const float*)d_in[10];
    const float* W_fc2  = (const float*)d_in[11];
    const float* b_fc2  = (const float*)d_in[12];

    char* ws = (char*)d_ws;
    size_t off = 0;
    auto alloc = [&](size_t bytes) -> char* {
        char* p = ws + off;
        off += (bytes + 255) & ~(size_t)255;
        return p;
    };
    unsigned short* WtA  = (unsigned short*)alloc((size_t)2304 * 768 * 2);
    unsigned short* WtP  = (unsigned short*)alloc((size_t)768 * 768 * 2);
    unsigned short* WtF  = (unsigned short*)alloc((size_t)3072 * 768 * 2);
    unsigned short* WtF2 = (unsigned short*)alloc((size_t)768 * 3072 * 2);
    unsigned short* bigA = (unsigned short*)alloc((size_t)8192 * 3072 * 2); // qkv, then gelu(fc)
    float*          x1   = (float*)alloc((size_t)8192 * 768 * 4);
    unsigned short* bufD = (unsigned short*)alloc((size_t)8192 * 768 * 2);  // h_ln / y / h_ln2
    unsigned short* vT   = (unsigned short*)alloc((size_t)48 * 64 * 2048 * 2);

    // weights -> bf16 transposed
    wtrans<<<dim3(72, 24), dim3(32, 8), 0, stream>>>(W_attn, WtA, 768, 2304);
    wtrans<<<dim3(24, 24), dim3(32, 8), 0, stream>>>(W_proj, WtP, 768, 768);
    wtrans<<<dim3(96, 24), dim3(32, 8), 0, stream>>>(W_fc, WtF, 768, 3072);
    wtrans<<<dim3(24, 96), dim3(32, 8), 0, stream>>>(W_fc2, WtF2, 3072, 768);
    // LN1: x -> bufD (bf16)
    ln_fwd<<<2048, 256, 0, stream>>>(x, ln1_g, ln1_b, bufD);
    // QKV: bufD @ WtA^T -> bigA (bf16, q scaled 1/8)
    gemm_bt<1><<<dim3(64, 18), 256, 0, stream>>>(bufD, WtA, b_attn, nullptr, bigA, 8192, 2304, 768);
    // V transpose
    vtrans<<<dim3(32, 48), 256, 0, stream>>>(bigA, vT);
    // attention -> bufD (= y, bf16)
    attn_fwd<<<dim3(32, 48), 256, 0, stream>>>(bigA, vT, bufD);
    // proj: y @ WtP^T + b + x -> x1 (fp32)
    gemm_bt<2><<<dim3(64, 6), 256, 0, stream>>>(bufD, WtP, b_proj, x, x1, 8192, 768, 768);
    // LN2: x1 -> bufD (bf16)
    ln_fwd<<<2048, 256, 0, stream>>>(x1, ln2_g, ln2_b, bufD);
    // FC + GELU: bufD @ WtF^T -> bigA (bf16)
    gemm_bt<3><<<dim3(64, 24), 256, 0, stream>>>(bufD, WtF, b_fc, nullptr, bigA, 8192, 3072, 768);
    // FC2: bigA @ WtF2^T + b + x1 -> d_out (fp32)
    gemm_bt<4><<<dim3(64, 6), 256, 0, stream>>>(bigA, WtF2, b_fc2, x1, (float*)d_out, 8192, 768, 3072);
}

// Round 2
// 284.935 us; speedup vs baseline: 1.4368x; 1.4368x over previous
//
#include <hip/hip_runtime.h>
#include <hip/hip_bf16.h>

typedef __attribute__((ext_vector_type(8))) short short8;     // 8 bf16 (MFMA frag)
typedef __attribute__((ext_vector_type(4))) float f32x4;      // MFMA acc frag
typedef __attribute__((ext_vector_type(8))) unsigned short u16x8;
typedef __attribute__((ext_vector_type(4))) unsigned short u16x4;

#define MFMA16(A, B, C) __builtin_amdgcn_mfma_f32_16x16x32_bf16(A, B, C, 0, 0, 0)

static __device__ __forceinline__ unsigned short f2bf(float f) {
    unsigned int u = __builtin_bit_cast(unsigned int, f);
    u += 0x7FFF + ((u >> 16) & 1);   // RNE
    return (unsigned short)(u >> 16);
}

static __device__ __forceinline__ unsigned int cvt_pk_bf16(float a, float b) {
    unsigned int r;
    asm("v_cvt_pk_bf16_f32 %0, %1, %2" : "=v"(r) : "v"(a), "v"(b));
    return r;
}

typedef const __attribute__((address_space(1))) unsigned int* gas_t;
typedef __attribute__((address_space(3))) unsigned int* las_t;
static __device__ __forceinline__ void gl_lds16(const void* g, void* l) {
    __builtin_amdgcn_global_load_lds((gas_t)g, (las_t)l, 16, 0, 0);
}

// ---------------------------------------------------------------------------
// Weight transpose + cast: W [K][N] fp32  ->  Wt [N][K] bf16
// ---------------------------------------------------------------------------
__global__ void wtrans(const float* __restrict__ W, unsigned short* __restrict__ Wt,
                       int K, int N) {
    __shared__ float tl[32][33];
    const int n0 = blockIdx.x * 32, k0 = blockIdx.y * 32;
    const int tx = threadIdx.x, ty = threadIdx.y;
#pragma unroll
    for (int i = 0; i < 4; i++)
        tl[ty + 8 * i][tx] = W[(long)(k0 + ty + 8 * i) * N + n0 + tx];
    __syncthreads();
#pragma unroll
    for (int i = 0; i < 4; i++)
        Wt[(long)(n0 + ty + 8 * i) * K + k0 + tx] = f2bf(tl[tx][ty + 8 * i]);
}

// ---------------------------------------------------------------------------
// LayerNorm: fp32 [rows][768] -> bf16 [rows][768].  One wave per row.
// ---------------------------------------------------------------------------
__global__ __launch_bounds__(256)
void ln_fwd(const float* __restrict__ x, const float* __restrict__ gw,
            const float* __restrict__ bw, unsigned short* __restrict__ out) {
    const int row = blockIdx.x * 4 + (threadIdx.x >> 6);
    const int ln = threadIdx.x & 63;
    const float4* xr = (const float4*)(x + (long)row * 768);
    float4 v[3];
    float s = 0.f;
#pragma unroll
    for (int j = 0; j < 3; j++) {
        v[j] = xr[ln + 64 * j];
        s += v[j].x + v[j].y + v[j].z + v[j].w;
    }
#pragma unroll
    for (int off = 32; off >= 1; off >>= 1) s += __shfl_xor(s, off);
    const float mean = s * (1.0f / 768.0f);
    float sq = 0.f;
#pragma unroll
    for (int j = 0; j < 3; j++) {
        float a = v[j].x - mean, b = v[j].y - mean, c = v[j].z - mean, d = v[j].w - mean;
        sq += a * a + b * b + c * c + d * d;
    }
#pragma unroll
    for (int off = 32; off >= 1; off >>= 1) sq += __shfl_xor(sq, off);
    const float rstd = rsqrtf(sq * (1.0f / 768.0f) + 1e-5f);
#pragma unroll
    for (int j = 0; j < 3; j++) {
        const int c = ln + 64 * j;
        float4 gg = ((const float4*)gw)[c];
        float4 bb = ((const float4*)bw)[c];
        u16x4 o;
        o[0] = f2bf((v[j].x - mean) * rstd * gg.x + bb.x);
        o[1] = f2bf((v[j].y - mean) * rstd * gg.y + bb.y);
        o[2] = f2bf((v[j].z - mean) * rstd * gg.z + bb.z);
        o[3] = f2bf((v[j].w - mean) * rstd * gg.w + bb.w);
        *(u16x4*)(out + (long)row * 768 + c * 4) = o;
    }
}

// ---------------------------------------------------------------------------
// GEMM  C[M,N] = A[M,K] (bf16) x Bt[N,K]^T (bf16) + bias, fused epilogues.
// m97 structure: 128x128 tile, BK=64, global_load_lds dwordx4 staging into
// linear [128][64] LDS with pre-swizzled global source (XOR involution on
// 16B chunks), swizzled ds_read_b128.  4 waves, 64x64/wave, 4x4 MFMA frags.
// MODE 1: qkv  -> bf16, cols<768 scaled by 0.125*log2(e)  (q pre-scale, exp2 domain)
// MODE 2: proj -> fp32 out = acc + bias + resid
// MODE 3: fc   -> bf16 out = gelu(acc + bias)
// MODE 4: fc2  -> fp32 out = acc + bias + resid
// ---------------------------------------------------------------------------
template <int MODE>
__global__ __launch_bounds__(256)
void gemm_bt(const unsigned short* __restrict__ A, const unsigned short* __restrict__ Bt,
             const float* __restrict__ bias, const float* __restrict__ resid,
             void* __restrict__ Out, int M, int N, int K) {
    __shared__ unsigned short Al[128 * 64];
    __shared__ unsigned short Bl[128 * 64];
    const int tid = threadIdx.x;
    const int wv = tid >> 6, ln = tid & 63;
    const int wr = wv >> 1, wc = wv & 1;
    const int g = ln >> 4, r = ln & 15;
    const int lr = ln >> 3, l8 = ln & 7;
    const int sw = l8 ^ lr;                 // staged logical chunk (row&7 == lr)
    const long mbase = (long)blockIdx.x * 128;
    const long nbase = (long)blockIdx.y * 128;

    f32x4 acc[4][4];
    const f32x4 zero = {0.f, 0.f, 0.f, 0.f};
#pragma unroll
    for (int m = 0; m < 4; m++)
#pragma unroll
        for (int n = 0; n < 4; n++) acc[m][n] = zero;

    const int rx = r & 7;
    for (int k0 = 0; k0 < K; k0 += 64) {
        __syncthreads();
#pragma unroll
        for (int p = 0; p < 4; p++) {
            const int row = p * 32 + wv * 8 + lr;
            gl_lds16(A + (mbase + row) * (long)K + k0 + sw * 8,
                     (char*)Al + (p * 32 + wv * 8) * 128);
            gl_lds16(Bt + (nbase + row) * (long)K + k0 + sw * 8,
                     (char*)Bl + (p * 32 + wv * 8) * 128);
        }
        __syncthreads();
#pragma unroll
        for (int ks = 0; ks < 2; ks++) {
            short8 af[4], bfr[4];
#pragma unroll
            for (int m = 0; m < 4; m++)
                af[m] = *(const short8*)(Al + (wr * 64 + m * 16 + r) * 64 + ((g + 4 * ks) ^ rx) * 8);
#pragma unroll
            for (int n = 0; n < 4; n++)
                bfr[n] = *(const short8*)(Bl + (wc * 64 + n * 16 + r) * 64 + ((g + 4 * ks) ^ rx) * 8);
#pragma unroll
            for (int m = 0; m < 4; m++)
#pragma unroll
                for (int n = 0; n < 4; n++) acc[m][n] = MFMA16(af[m], bfr[n], acc[m][n]);
        }
    }

#pragma unroll
    for (int n = 0; n < 4; n++) {
        const long col = nbase + wc * 64 + n * 16 + r;
        const float bc = bias[col];
#pragma unroll
        for (int m = 0; m < 4; m++) {
#pragma unroll
            for (int i = 0; i < 4; i++) {
                const long row = mbase + wr * 64 + m * 16 + g * 4 + i;
                float v = acc[m][n][i] + bc;
                if constexpr (MODE == 1) {
                    if (col < 768) v *= 0.18033688011112042f;   // 0.125 * log2(e)
                    ((unsigned short*)Out)[row * N + col] = f2bf(v);
                } else if constexpr (MODE == 2 || MODE == 4) {
                    ((float*)Out)[row * N + col] = v + resid[row * N + col];
                } else {
                    float u = 0.7978845608028654f * (v + 0.044715f * v * v * v);
                    float gl = 0.5f * v * (1.0f + tanhf(u));
                    ((unsigned short*)Out)[row * N + col] = f2bf(gl);
                }
            }
        }
    }
}

// ---------------------------------------------------------------------------
// V transpose: qkv[b][t][1536 + h*64 + d] -> vT[bh][d][t]   (bf16, linear)
// ---------------------------------------------------------------------------
__global__ __launch_bounds__(256)
void vtrans(const unsigned short* __restrict__ qkv, unsigned short* __restrict__ vT) {
    const int t0 = blockIdx.x * 64;
    const int bh = blockIdx.y;
    const int b = bh / 12, h = bh % 12;
    __shared__ unsigned short tl[64 * 72];
    const int tid = threadIdx.x;
#pragma unroll
    for (int p = 0; p < 2; p++) {
        int idx = p * 256 + tid;
        int row = idx >> 3, blk = idx & 7;
        int sb = (blk + row) % 9;
        *(u16x8*)(tl + row * 72 + sb * 8) =
            *(const u16x8*)(qkv + ((long)(b * 2048 + t0 + row)) * 2304 + 1536 + h * 64 + blk * 8);
    }
    __syncthreads();
#pragma unroll
    for (int p = 0; p < 2; p++) {
        int idx = p * 256 + tid;
        int d = idx >> 3, tc = (idx & 7) * 8;
        u16x8 v;
#pragma unroll
        for (int j = 0; j < 8; j++) {
            int t = tc + j;
            int sb = ((d >> 3) + t) % 9;
            v[j] = tl[t * 72 + sb * 8 + (d & 7)];
        }
        *(u16x8*)(vT + ((long)(bh * 64 + d)) * 2048 + t0 + tc) = v;
    }
}

// ---------------------------------------------------------------------------
// Flash attention fwd (causal), exp2 domain (q pre-scaled by 0.125*log2e).
// Block = one (b,h) x a PAIR of q-tiles (qt, 31-qt): uniform 33 k-tiles/block.
// 4 waves x 16 q-rows, swapped QK^T; K/V staged via global_load_lds into
// linear [64][64] LDS with pre-swizzled source; defer-max online softmax;
// v_cvt_pk_bf16_f32 packing.
// ---------------------------------------------------------------------------
__global__ __launch_bounds__(256)
void attn_fwd(const unsigned short* __restrict__ qkv, const unsigned short* __restrict__ vT,
              unsigned short* __restrict__ y) {
    const int pair = blockIdx.x;                 // 0..15
    const int bh = blockIdx.y;
    const int b = bh / 12, h = bh % 12;
    __shared__ unsigned short Kl[64 * 64], Vl[64 * 64], Pl[64 * 72];
    const int tid = threadIdx.x;
    const int wv = tid >> 6, ln = tid & 63;
    const int g = ln >> 4, r = ln & 15;
    const int lr = ln >> 3, l8 = ln & 7;
    const int sw = l8 ^ lr;                      // staging chunk swizzle
    const int rx = r & 7;
    const f32x4 zero = {0.f, 0.f, 0.f, 0.f};

#pragma unroll 1
    for (int qi = 0; qi < 2; qi++) {
        const int qt = qi ? (31 - pair) : pair;
        const int q0 = qt * 64;
        const int q = wv * 16 + r;               // q-local row this lane owns
        const long qoff = ((long)(b * 2048 + q0 + q)) * 2304 + h * 64;
        short8 bq0 = *(const short8*)(qkv + qoff + g * 8);
        short8 bq1 = *(const short8*)(qkv + qoff + 32 + g * 8);

        float mrow = -1e30f, lrow = 0.0f;
        f32x4 oacc[4];
#pragma unroll
        for (int f = 0; f < 4; f++) oacc[f] = zero;

        for (int kt = 0; kt <= qt; ++kt) {
            __syncthreads();
#pragma unroll
            for (int p = 0; p < 2; p++) {
                const int row = wv * 8 + p * 32 + lr;
                gl_lds16(qkv + ((long)(b * 2048 + kt * 64 + row)) * 2304 + 768 + h * 64 + sw * 8,
                         (char*)Kl + (wv * 8 + p * 32) * 128);
                gl_lds16(vT + ((long)(bh * 64 + row)) * 2048 + kt * 64 + sw * 8,
                         (char*)Vl + (wv * 8 + p * 32) * 128);
            }
            __syncthreads();

            f32x4 s[4];
#pragma unroll
            for (int kf = 0; kf < 4; kf++) {
                short8 a0 = *(const short8*)(Kl + (kf * 16 + r) * 64 + (g ^ rx) * 8);
                short8 a1 = *(const short8*)(Kl + (kf * 16 + r) * 64 + ((g + 4) ^ rx) * 8);
                s[kf] = MFMA16(a0, bq0, zero);
                s[kf] = MFMA16(a1, bq1, s[kf]);
            }
            if (kt == qt) {   // diagonal tile: mask k_local > q_local
#pragma unroll
                for (int kf = 0; kf < 4; kf++)
#pragma unroll
                    for (int i = 0; i < 4; i++)
                        if (kf * 16 + g * 4 + i > q) s[kf][i] = -1e30f;
            }
            // ---- online softmax (log2 domain), defer-max
            float tmax = -1e30f;
#pragma unroll
            for (int kf = 0; kf < 4; kf++)
#pragma unroll
                for (int i = 0; i < 4; i++) tmax = fmaxf(tmax, s[kf][i]);
            tmax = fmaxf(tmax, __shfl_xor(tmax, 16));
            tmax = fmaxf(tmax, __shfl_xor(tmax, 32));
            if (__any(tmax > mrow + 6.0f)) {     // rescale only on real growth
                const float mnew = fmaxf(mrow, tmax);
                const float rs = __builtin_amdgcn_exp2f(mrow - mnew);
                lrow *= rs;
#pragma unroll
                for (int f = 0; f < 4; f++) oacc[f] *= rs;
                mrow = mnew;
            }
            float pv[4][4];
            float psum = 0.f;
#pragma unroll
            for (int kf = 0; kf < 4; kf++)
#pragma unroll
                for (int i = 0; i < 4; i++) {
                    pv[kf][i] = __builtin_amdgcn_exp2f(s[kf][i] - mrow);
                    psum += pv[kf][i];
                }
            psum += __shfl_xor(psum, 16);
            psum += __shfl_xor(psum, 32);
            lrow += psum;

            // ---- P^T -> LDS (wave-local), packed via v_cvt_pk_bf16_f32
#pragma unroll
            for (int kf = 0; kf < 4; kf++) {
                uint2 w;
                w.x = cvt_pk_bf16(pv[kf][0], pv[kf][1]);
                w.y = cvt_pk_bf16(pv[kf][2], pv[kf][3]);
                *(uint2*)(Pl + q * 72 + kf * 16 + g * 4) = w;
            }
            short8 pb0 = *(const short8*)(Pl + q * 72 + g * 8);
            short8 pb1 = *(const short8*)(Pl + q * 72 + 32 + g * 8);
#pragma unroll
            for (int f = 0; f < 4; f++) {
                short8 va0 = *(const short8*)(Vl + (f * 16 + r) * 64 + (g ^ rx) * 8);
                short8 va1 = *(const short8*)(Vl + (f * 16 + r) * 64 + ((g + 4) ^ rx) * 8);
                oacc[f] = MFMA16(va0, pb0, oacc[f]);
                oacc[f] = MFMA16(va1, pb1, oacc[f]);
            }
        }

        // ---- epilogue: O^T frags -> LDS (reuse Pl) -> coalesced global
        const float inv = 1.0f / lrow;
#pragma unroll
        for (int f = 0; f < 4; f++) {
            uint2 w;
            w.x = cvt_pk_bf16(oacc[f][0] * inv, oacc[f][1] * inv);
            w.y = cvt_pk_bf16(oacc[f][2] * inv, oacc[f][3] * inv);
            *(uint2*)(Pl + q * 72 + f * 16 + g * 4) = w;
        }
        __syncthreads();
#pragma unroll
        for (int p = 0; p < 2; p++) {
            int idx = p * 256 + tid;
            int row = idx >> 3, cc = (idx & 7) * 8;
            *(u16x8*)(y + ((long)(b * 2048 + q0 + row)) * 768 + h * 64 + cc) =
                *(const u16x8*)(Pl + row * 72 + cc);
        }
    }
}

// ---------------------------------------------------------------------------
extern "C" void kernel_launch(void* const* d_in, const int* in_sizes, int n_in,
                              void* d_out, int out_size, void* d_ws, size_t ws_size,
                              hipStream_t stream) {
    const float* x      = (const float*)d_in[0];
    const float* ln1_g  = (const float*)d_in[1];
    const float* ln1_b  = (const float*)d_in[2];
    const float* W_attn = (const float*)d_in[3];
    const float* b_attn = (const float*)d_in[4];
    const float* W_proj = (const float*)d_in[5];
    const float* b_proj = (const float*)d_in[6];
    const float* ln2_g  = (const float*)d_in[7];
    const float* ln2_b  = (const float*)d_in[8];
    const float* W_fc   = (const float*)d_in[9];
    const float* b_fc   = (const float*)d_in[10];
    const float* W_fc2  = (const float*)d_in[11];
    const float* b_fc2  = (const float*)d_in[12];

    char* ws = (char*)d_ws;
    size_t off = 0;
    auto alloc = [&](size_t bytes) -> char* {
        char* p = ws + off;
        off += (bytes + 255) & ~(size_t)255;
        return p;
    };
    unsigned short* WtA  = (unsigned short*)alloc((size_t)2304 * 768 * 2);
    unsigned short* WtP  = (unsigned short*)alloc((size_t)768 * 768 * 2);
    unsigned short* WtF  = (unsigned short*)alloc((size_t)3072 * 768 * 2);
    unsigned short* WtF2 = (unsigned short*)alloc((size_t)768 * 3072 * 2);
    unsigned short* bigA = (unsigned short*)alloc((size_t)8192 * 3072 * 2); // qkv, then gelu(fc)
    float*          x1   = (float*)alloc((size_t)8192 * 768 * 4);
    unsigned short* bufD = (unsigned short*)alloc((size_t)8192 * 768 * 2);  // h_ln / y / h_ln2
    unsigned short* vT   = (unsigned short*)alloc((size_t)48 * 64 * 2048 * 2);

    // weights -> bf16 transposed
    wtrans<<<dim3(72, 24), dim3(32, 8), 0, stream>>>(W_attn, WtA, 768, 2304);
    wtrans<<<dim3(24, 24), dim3(32, 8), 0, stream>>>(W_proj, WtP, 768, 768);
    wtrans<<<dim3(96, 24), dim3(32, 8), 0, stream>>>(W_fc, WtF, 768, 3072);
    wtrans<<<dim3(24, 96), dim3(32, 8), 0, stream>>>(W_fc2, WtF2, 3072, 768);
    // LN1: x -> bufD (bf16)
    ln_fwd<<<2048, 256, 0, stream>>>(x, ln1_g, ln1_b, bufD);
    // QKV: bufD @ WtA^T -> bigA (bf16, q scaled 0.125*log2e for exp2-domain softmax)
    gemm_bt<1><<<dim3(64, 18), 256, 0, stream>>>(bufD, WtA, b_attn, nullptr, bigA, 8192, 2304, 768);
    // V transpose
    vtrans<<<dim3(32, 48), 256, 0, stream>>>(bigA, vT);
    // attention -> bufD (= y, bf16); paired q-tiles for uniform work
    attn_fwd<<<dim3(16, 48), 256, 0, stream>>>(bigA, vT, bufD);
    // proj: y @ WtP^T + b + x -> x1 (fp32)
    gemm_bt<2><<<dim3(64, 6), 256, 0, stream>>>(bufD, WtP, b_proj, x, x1, 8192, 768, 768);
    // LN2: x1 -> bufD (bf16)
    ln_fwd<<<2048, 256, 0, stream>>>(x1, ln2_g, ln2_b, bufD);
    // FC + GELU: bufD @ WtF^T -> bigA (bf16)
    gemm_bt<3><<<dim3(64, 24), 256, 0, stream>>>(bufD, WtF, b_fc, nullptr, bigA, 8192, 3072, 768);
    // FC2: bigA @ WtF2^T + b + x1 -> d_out (fp32)
    gemm_bt<4><<<dim3(64, 6), 256, 0, stream>>>(bigA, WtF2, b_fc2, x1, (float*)d_out, 8192, 768, 3072);
}